// Round 7
// baseline (603.269 us; speedup 1.0000x reference)
//
#include <hip/hip_runtime.h>
#include <math.h>

#define NCL 21
#define CIN 256
#define HW 4096
#define PADK 24
#define NB 2

static __device__ __forceinline__ float fastrcp(float x) {
  return __builtin_amdgcn_rcpf(x);
}

// ---------------------------------------------------------------------------
// Kernel A: f1/f2 = 1x1 conv (w @ feat + b), PLUS the out 128->64 bilinear
// downsample (merged k_outr), PLUS zero-fill of lbuf/corr_out (replaces
// memsets). Block = 16 q x 16 c-chunks of 16 channels; LDS reduction.
#define QT 16
#define CCH 16
__global__ __launch_bounds__(256) void k_feat(
    const float* __restrict__ feat, const float* __restrict__ w1,
    const float* __restrict__ b1, const float* __restrict__ w2,
    const float* __restrict__ b2, const float* __restrict__ outp,
    float* __restrict__ f1T, float* __restrict__ f2, float* __restrict__ otT,
    float* __restrict__ lbuf, float* __restrict__ corr_out) {
  const int t = threadIdx.x;
  const int bid = blockIdx.y * (HW / QT) + blockIdx.x;  // 0..511
  // zero-fill: corr_out = 43008 float4 (84/block), lbuf = 8192 f (16/block)
  {
    float4* co4 = (float4*)corr_out;
    const int base = bid * 84;
    for (int o = t; o < 84; o += 256) co4[base + o] = make_float4(0, 0, 0, 0);
    if (t < 16) lbuf[bid * 16 + t] = 0.f;
  }
  // merged k_outr: 172032 elements, 336 per block
  for (int o = t; o < 336; o += 256) {
    int idx = bid * 336 + o;
    int p = idx & (HW - 1);
    int nk = idx >> 12;
    int i = p >> 6, j = p & 63;
    double sy = (double)i * (127.0 / 63.0);
    double sx = (double)j * (127.0 / 63.0);
    int y0 = (int)sy, x0 = (int)sx;
    float wy = (float)(sy - y0), wx = (float)(sx - x0);
    int y1 = min(y0 + 1, 127), x1 = min(x0 + 1, 127);
    const float* src = outp + (size_t)nk * (128 * 128);
    float v00 = src[y0 * 128 + x0], v10 = src[y1 * 128 + x0];
    float v01 = src[y0 * 128 + x1], v11 = src[y1 * 128 + x1];
    float r0 = v00 * (1.f - wy) + v10 * wy;
    float r1 = v01 * (1.f - wy) + v11 * wy;
    float val = r0 * (1.f - wx) + r1 * wx;
    int n = nk / NCL, c = nk % NCL;
    otT[((size_t)n * HW + p) * PADK + c] = val;
  }
  const int qi = t & 15, ch = t >> 4;
  const int n = blockIdx.y;
  const int q = blockIdx.x * QT + qi;
  const int c0 = ch * CCH;
  const float* fp = feat + ((size_t)n * CIN + c0) * HW + q;
  float a1[NCL], a2[NCL];
#pragma unroll
  for (int k = 0; k < NCL; ++k) { a1[k] = 0.f; a2[k] = 0.f; }
#pragma unroll
  for (int cc = 0; cc < CCH; ++cc) {
    float v = fp[(size_t)cc * HW];
#pragma unroll
    for (int k = 0; k < NCL; ++k) {
      a1[k] = fmaf(v, w1[k * CIN + c0 + cc], a1[k]);
      a2[k] = fmaf(v, w2[k * CIN + c0 + cc], a2[k]);
    }
  }
  __shared__ float p1[CCH][QT][NCL];
  __shared__ float p2[CCH][QT][NCL];
#pragma unroll
  for (int k = 0; k < NCL; ++k) { p1[ch][qi][k] = a1[k]; p2[ch][qi][k] = a2[k]; }
  __syncthreads();
  for (int o = t; o < QT * NCL; o += 256) {
    int qq = o & 15, k = o >> 4;
    float s1 = b1[k], s2 = b2[k];
#pragma unroll
    for (int c = 0; c < CCH; ++c) { s1 += p1[c][qq][k]; s2 += p2[c][qq][k]; }
    int qg = blockIdx.x * QT + qq;
    f1T[((size_t)n * HW + qg) * PADK + k] = s1;
    f2[((size_t)n * NCL + k) * HW + qg] = s2;
  }
}

// ---------------------------------------------------------------------------
// Kernel M: sampled-row chain map. head[p] = first slot i with index[i]==p,
// nxt[i] = next slot with the same p (-1 end). Handles duplicate indices.
__global__ __launch_bounds__(1024) void k_map(const int* __restrict__ index,
                                              int* __restrict__ head,
                                              int* __restrict__ nxt) {
  const int t = threadIdx.x;
  for (int o = t; o < HW; o += 1024) head[o] = -1;
  __syncthreads();
  if (t == 0) {
    for (int i = 0; i < 128; ++i) {
      int p = index[i];
      p = max(0, min(p, HW - 1));
      nxt[i] = head[p];
      head[p] = i;
    }
  }
}

// ---------------------------------------------------------------------------
// Kernel C: l[n][p] += sum_q exp(S[n][p][q]) over a q-quarter (r3 structure).
// NEW: for sampled p (head[p]>=0) also park the unnormalized exp row in the
// out0 slot(s) — replaces the separate k_rows kernel; min/max norm downstream
// is invariant to the softmax denominator.
#define PT 16
__global__ __launch_bounds__(256) void k_stats(
    const float* __restrict__ f1T, const float* __restrict__ f2,
    float* __restrict__ l, const int* __restrict__ head,
    const int* __restrict__ nxt, float* __restrict__ out0) {
  const int t = threadIdx.x;
  const int n = blockIdx.z;
  const int pbase = blockIdx.x * PT;
  const int q0 = blockIdx.y * 1024 + t * 4;
  const float* f2n = f2 + (size_t)n * NCL * HW;
  const float* f1n = f1T + ((size_t)n * HW + pbase) * PADK;
  const float SCALE = 1.0f / sqrtf(21.0f);
  float4 fq[NCL];
#pragma unroll
  for (int k = 0; k < NCL; ++k)
    fq[k] = *(const float4*)(f2n + (size_t)k * HW + q0);
  float sums[PT];
#pragma unroll
  for (int p = 0; p < PT; ++p) {
    const float* f1p = f1n + p * PADK;  // uniform -> s_load
    float s0 = 0.f, s1 = 0.f, s2 = 0.f, s3 = 0.f;
#pragma unroll
    for (int k = 0; k < NCL; ++k) {
      float a = f1p[k];
      s0 = fmaf(a, fq[k].x, s0);
      s1 = fmaf(a, fq[k].y, s1);
      s2 = fmaf(a, fq[k].z, s2);
      s3 = fmaf(a, fq[k].w, s3);
    }
    float e0 = __expf(s0 * SCALE), e1 = __expf(s1 * SCALE);
    float e2 = __expf(s2 * SCALE), e3 = __expf(s3 * SCALE);
    sums[p] = e0 + e1 + e2 + e3;
    int slot = head[pbase + p];  // uniform scalar load; usually -1
    while (slot >= 0) {          // wave-uniform loop
      *(float4*)(out0 + ((size_t)n * 128 + slot) * (128 * 128) + q0) =
          make_float4(e0, e1, e2, e3);
      slot = nxt[slot];
    }
  }
  __shared__ float part[4][PT];
  const int wave = t >> 6, lane = t & 63;
#pragma unroll
  for (int p = 0; p < PT; ++p) {
    float s = sums[p];
    for (int off = 32; off > 0; off >>= 1) s += __shfl_xor(s, off, 64);
    if (lane == 0) part[wave][p] = s;
  }
  __syncthreads();
  if (t < PT) {
    float tot = part[0][t] + part[1][t] + part[2][t] + part[3][t];
    atomicAdd(l + (size_t)n * HW + pbase + t, tot);
  }
}

// ---------------------------------------------------------------------------
// Kernel D: corr_out[n][c][q] += sum_p otT'[n][p][c] * exp(S'[p][q]).
// SCALE folded into staged f1, rcp(l) folded into staged ot. DPS=32 ->
// 2048 blocks = 8 blocks/CU = 32 waves/CU (VGPR capped 64 via bounds).
#define DPS 32
__global__ __launch_bounds__(256, 8) void k_corrout(
    const float* __restrict__ f1T, const float* __restrict__ f2,
    const float* __restrict__ otT, const float* __restrict__ l,
    float* __restrict__ corr_out) {
  __shared__ float sf1[DPS * PADK];  // 768 floats
  __shared__ float sot[DPS * PADK];
  const int t = threadIdx.x;
  const int n = blockIdx.z;
  const int q0 = blockIdx.x * 512 + t * 2;
  const int pbase = blockIdx.y * DPS;
  const float SCALE = 1.0f / sqrtf(21.0f);
  const float4* gf1 = (const float4*)(f1T + ((size_t)n * HW + pbase) * PADK);
  const float4* got = (const float4*)(otT + ((size_t)n * HW + pbase) * PADK);
  const float* lp = l + (size_t)n * HW + pbase;
  for (int o = t; o < 192; o += 256) {
    float4 a = gf1[o];
    a.x *= SCALE; a.y *= SCALE; a.z *= SCALE; a.w *= SCALE;
    ((float4*)sf1)[o] = a;
    float il = fastrcp(lp[o / 6]);  // 6 float4 per PADK row
    float4 v = got[o];
    v.x *= il; v.y *= il; v.z *= il; v.w *= il;
    ((float4*)sot)[o] = v;
  }
  __syncthreads();
  const float* f2n = f2 + (size_t)n * NCL * HW;
  float2 fq[NCL];
#pragma unroll
  for (int k = 0; k < NCL; ++k)
    fq[k] = *(const float2*)(f2n + (size_t)k * HW + q0);
  float2 acc[NCL];
#pragma unroll
  for (int k = 0; k < NCL; ++k) acc[k] = make_float2(0.f, 0.f);
#pragma unroll 1
  for (int p = 0; p < DPS; ++p) {
    const float* f1p = sf1 + p * PADK;
    const float* otp = sot + p * PADK;
    float s0 = 0.f, s1 = 0.f;
#pragma unroll
    for (int k4 = 0; k4 < 5; ++k4) {
      float4 a = *(const float4*)(f1p + k4 * 4);
      s0 = fmaf(a.x, fq[k4 * 4 + 0].x, s0);
      s1 = fmaf(a.x, fq[k4 * 4 + 0].y, s1);
      s0 = fmaf(a.y, fq[k4 * 4 + 1].x, s0);
      s1 = fmaf(a.y, fq[k4 * 4 + 1].y, s1);
      s0 = fmaf(a.z, fq[k4 * 4 + 2].x, s0);
      s1 = fmaf(a.z, fq[k4 * 4 + 2].y, s1);
      s0 = fmaf(a.w, fq[k4 * 4 + 3].x, s0);
      s1 = fmaf(a.w, fq[k4 * 4 + 3].y, s1);
    }
    {
      float a20 = f1p[20];
      s0 = fmaf(a20, fq[20].x, s0);
      s1 = fmaf(a20, fq[20].y, s1);
    }
    float w0 = __expf(s0);
    float w1 = __expf(s1);
#pragma unroll
    for (int c4 = 0; c4 < 5; ++c4) {
      float4 o = *(const float4*)(otp + c4 * 4);
      acc[c4 * 4 + 0].x = fmaf(o.x, w0, acc[c4 * 4 + 0].x);
      acc[c4 * 4 + 0].y = fmaf(o.x, w1, acc[c4 * 4 + 0].y);
      acc[c4 * 4 + 1].x = fmaf(o.y, w0, acc[c4 * 4 + 1].x);
      acc[c4 * 4 + 1].y = fmaf(o.y, w1, acc[c4 * 4 + 1].y);
      acc[c4 * 4 + 2].x = fmaf(o.z, w0, acc[c4 * 4 + 2].x);
      acc[c4 * 4 + 2].y = fmaf(o.z, w1, acc[c4 * 4 + 2].y);
      acc[c4 * 4 + 3].x = fmaf(o.w, w0, acc[c4 * 4 + 3].x);
      acc[c4 * 4 + 3].y = fmaf(o.w, w1, acc[c4 * 4 + 3].y);
    }
    {
      float o20 = otp[20];
      acc[20].x = fmaf(o20, w0, acc[20].x);
      acc[20].y = fmaf(o20, w1, acc[20].y);
    }
  }
  float* co = corr_out + (size_t)n * NCL * HW + q0;
#pragma unroll
  for (int c = 0; c < NCL; ++c) {
    atomicAdd(co + (size_t)c * HW + 0, acc[c].x);
    atomicAdd(co + (size_t)c * HW + 1, acc[c].y);
  }
}

// ---------------------------------------------------------------------------
// Kernel E2: parked row -> bilinear 64->128 (in-kernel table) -> min/max norm
// -> >0.5 booleans as 1.0/0.0 (overwrites slot). 1024 threads.
__global__ __launch_bounds__(1024) void k_norm(float* __restrict__ out0) {
  __shared__ float row[HW];
  __shared__ float redmn[16], redmx[16];
  __shared__ float wt[128];
  __shared__ int it[128];
  const int t = threadIdx.x;
  const int i = blockIdx.x;
  const int n = blockIdx.y;
  if (t < 128) {
    double s = (double)t * (63.0 / 127.0);
    int i0 = (int)s;
    wt[t] = (float)(s - i0);
    it[t] = i0;
  }
  float* slot = out0 + ((size_t)n * 128 + i) * (128 * 128);
  *(float4*)(row + t * 4) = *(const float4*)(slot + t * 4);
  __syncthreads();
  float vv[16];
  float lmn = 1e30f, lmx = -1e30f;
#pragma unroll
  for (int j = 0; j < 16; ++j) {
    int pix = t + j * 1024;
    int yy = pix >> 7, xx = pix & 127;
    int y0 = it[yy], x0 = it[xx];
    float wy = wt[yy], wx = wt[xx];
    int y1 = min(y0 + 1, 63), x1 = min(x0 + 1, 63);
    float r0 = row[y0 * 64 + x0] * (1.f - wy) + row[y1 * 64 + x0] * wy;
    float r1 = row[y0 * 64 + x1] * (1.f - wy) + row[y1 * 64 + x1] * wy;
    float v = r0 * (1.f - wx) + r1 * wx;
    vv[j] = v;
    lmn = fminf(lmn, v);
    lmx = fmaxf(lmx, v);
  }
  for (int off = 32; off > 0; off >>= 1) {
    lmn = fminf(lmn, __shfl_xor(lmn, off, 64));
    lmx = fmaxf(lmx, __shfl_xor(lmx, off, 64));
  }
  const int wave = t >> 6, lane = t & 63;
  if (lane == 0) { redmn[wave] = lmn; redmx[wave] = lmx; }
  __syncthreads();
  if (t == 0) {
    float mn = redmn[0], mx = redmx[0];
#pragma unroll
    for (int wv = 1; wv < 16; ++wv) {
      mn = fminf(mn, redmn[wv]);
      mx = fmaxf(mx, redmx[wv]);
    }
    redmn[0] = mn;
    redmx[0] = mx;
  }
  __syncthreads();
  const float mn = redmn[0];
  const float rng = redmx[0] - mn;
#pragma unroll
  for (int j = 0; j < 16; ++j) {
    int pix = t + j * 1024;
    float nrm = (vv[j] - mn) / rng;
    slot[pix] = (nrm > 0.5f) ? 1.0f : 0.0f;
  }
}

// ---------------------------------------------------------------------------
extern "C" void kernel_launch(void* const* d_in, const int* in_sizes, int n_in,
                              void* d_out, int out_size, void* d_ws,
                              size_t ws_size, hipStream_t stream) {
  (void)in_sizes; (void)n_in; (void)out_size; (void)ws_size;
  const float* feat = (const float*)d_in[0];
  const float* out  = (const float*)d_in[1];
  const float* w1   = (const float*)d_in[2];
  const float* b1   = (const float*)d_in[3];
  const float* w2   = (const float*)d_in[4];
  const float* b2   = (const float*)d_in[5];
  const int* index  = (const int*)d_in[6];

  float* ws   = (float*)d_ws;
  float* f1T  = ws;                                   // 2*4096*24 = 196608
  float* f2   = ws + 196608;                          // 2*21*4096 = 172032
  float* otT  = ws + 196608 + 172032;                 // 196608
  float* lbuf = ws + 196608 + 172032 + 196608;        // 8192
  int*   head = (int*)(lbuf + 8192);                  // 4096
  int*   nxt  = head + 4096;                          // 128

  float* out0     = (float*)d_out;                    // 2*128*128*128
  float* corr_out = out0 + (size_t)NB * 128 * 128 * 128;  // 2*21*4096

  k_feat<<<dim3(HW / QT, 2), 256, 0, stream>>>(feat, w1, b1, w2, b2, out, f1T,
                                               f2, otT, lbuf, corr_out);
  k_map<<<dim3(1), 1024, 0, stream>>>(index, head, nxt);
  k_stats<<<dim3(HW / PT, 4, 2), 256, 0, stream>>>(f1T, f2, lbuf, head, nxt,
                                                   out0);
  k_corrout<<<dim3(8, HW / DPS, 2), 256, 0, stream>>>(f1T, f2, otT, lbuf,
                                                      corr_out);
  k_norm<<<dim3(128, 2), 1024, 0, stream>>>(out0);
}

// Round 8
// 348.409 us; speedup vs baseline: 1.7315x; 1.7315x over previous
//
#include <hip/hip_runtime.h>
#include <math.h>

#define NCL 21
#define CIN 256
#define HW 4096
#define PADK 24
#define NB 2

static __device__ __forceinline__ float fastrcp(float x) {
  return __builtin_amdgcn_rcpf(x);
}

// ---------------------------------------------------------------------------
// Kernel A: f1/f2 = 1x1 conv (w @ feat + b), PLUS the out 128->64 bilinear
// downsample (merged k_outr), PLUS zero-fill of lbuf/corr_out (replaces
// memsets). Block = 16 q x 16 c-chunks of 16 channels; LDS reduction.
#define QT 16
#define CCH 16
__global__ __launch_bounds__(256) void k_feat(
    const float* __restrict__ feat, const float* __restrict__ w1,
    const float* __restrict__ b1, const float* __restrict__ w2,
    const float* __restrict__ b2, const float* __restrict__ outp,
    float* __restrict__ f1T, float* __restrict__ f2, float* __restrict__ otT,
    float* __restrict__ lbuf, float* __restrict__ corr_out) {
  const int t = threadIdx.x;
  const int bid = blockIdx.y * (HW / QT) + blockIdx.x;  // 0..511
  {
    float4* co4 = (float4*)corr_out;
    const int base = bid * 84;
    for (int o = t; o < 84; o += 256) co4[base + o] = make_float4(0, 0, 0, 0);
    if (t < 16) lbuf[bid * 16 + t] = 0.f;
  }
  // merged k_outr: 172032 elements, 336 per block
  for (int o = t; o < 336; o += 256) {
    int idx = bid * 336 + o;
    int p = idx & (HW - 1);
    int nk = idx >> 12;
    int i = p >> 6, j = p & 63;
    double sy = (double)i * (127.0 / 63.0);
    double sx = (double)j * (127.0 / 63.0);
    int y0 = (int)sy, x0 = (int)sx;
    float wy = (float)(sy - y0), wx = (float)(sx - x0);
    int y1 = min(y0 + 1, 127), x1 = min(x0 + 1, 127);
    const float* src = outp + (size_t)nk * (128 * 128);
    float v00 = src[y0 * 128 + x0], v10 = src[y1 * 128 + x0];
    float v01 = src[y0 * 128 + x1], v11 = src[y1 * 128 + x1];
    float r0 = v00 * (1.f - wy) + v10 * wy;
    float r1 = v01 * (1.f - wy) + v11 * wy;
    float val = r0 * (1.f - wx) + r1 * wx;
    int n = nk / NCL, c = nk % NCL;
    otT[((size_t)n * HW + p) * PADK + c] = val;
  }
  const int qi = t & 15, ch = t >> 4;
  const int n = blockIdx.y;
  const int q = blockIdx.x * QT + qi;
  const int c0 = ch * CCH;
  const float* fp = feat + ((size_t)n * CIN + c0) * HW + q;
  float a1[NCL], a2[NCL];
#pragma unroll
  for (int k = 0; k < NCL; ++k) { a1[k] = 0.f; a2[k] = 0.f; }
#pragma unroll
  for (int cc = 0; cc < CCH; ++cc) {
    float v = fp[(size_t)cc * HW];
#pragma unroll
    for (int k = 0; k < NCL; ++k) {
      a1[k] = fmaf(v, w1[k * CIN + c0 + cc], a1[k]);
      a2[k] = fmaf(v, w2[k * CIN + c0 + cc], a2[k]);
    }
  }
  __shared__ float p1[CCH][QT][NCL];
  __shared__ float p2[CCH][QT][NCL];
#pragma unroll
  for (int k = 0; k < NCL; ++k) { p1[ch][qi][k] = a1[k]; p2[ch][qi][k] = a2[k]; }
  __syncthreads();
  for (int o = t; o < QT * NCL; o += 256) {
    int qq = o & 15, k = o >> 4;
    float s1 = b1[k], s2 = b2[k];
#pragma unroll
    for (int c = 0; c < CCH; ++c) { s1 += p1[c][qq][k]; s2 += p2[c][qq][k]; }
    int qg = blockIdx.x * QT + qq;
    f1T[((size_t)n * HW + qg) * PADK + k] = s1;
    f2[((size_t)n * NCL + k) * HW + qg] = s2;
  }
}

// ---------------------------------------------------------------------------
// Kernel M: sampled-row chain map (handles duplicate indices).
__global__ __launch_bounds__(1024) void k_map(const int* __restrict__ index,
                                              int* __restrict__ head,
                                              int* __restrict__ nxt) {
  const int t = threadIdx.x;
  for (int o = t; o < HW; o += 1024) head[o] = -1;
  __syncthreads();
  if (t == 0) {
    for (int i = 0; i < 128; ++i) {
      int p = index[i];
      p = max(0, min(p, HW - 1));
      nxt[i] = head[p];
      head[p] = i;
    }
  }
}

// ---------------------------------------------------------------------------
// Kernel C: l[n][p] += sum_q exp(S[n][p][q]) over a q-quarter; sampled rows
// parked unnormalized in the out0 slots (min/max norm is scale-invariant).
#define PT 16
__global__ __launch_bounds__(256) void k_stats(
    const float* __restrict__ f1T, const float* __restrict__ f2,
    float* __restrict__ l, const int* __restrict__ head,
    const int* __restrict__ nxt, float* __restrict__ out0) {
  const int t = threadIdx.x;
  const int n = blockIdx.z;
  const int pbase = blockIdx.x * PT;
  const int q0 = blockIdx.y * 1024 + t * 4;
  const float* f2n = f2 + (size_t)n * NCL * HW;
  const float* f1n = f1T + ((size_t)n * HW + pbase) * PADK;
  const float SCALE = 1.0f / sqrtf(21.0f);
  float4 fq[NCL];
#pragma unroll
  for (int k = 0; k < NCL; ++k)
    fq[k] = *(const float4*)(f2n + (size_t)k * HW + q0);
  float sums[PT];
#pragma unroll
  for (int p = 0; p < PT; ++p) {
    const float* f1p = f1n + p * PADK;  // uniform -> s_load
    float s0 = 0.f, s1 = 0.f, s2 = 0.f, s3 = 0.f;
#pragma unroll
    for (int k = 0; k < NCL; ++k) {
      float a = f1p[k];
      s0 = fmaf(a, fq[k].x, s0);
      s1 = fmaf(a, fq[k].y, s1);
      s2 = fmaf(a, fq[k].z, s2);
      s3 = fmaf(a, fq[k].w, s3);
    }
    float e0 = __expf(s0 * SCALE), e1 = __expf(s1 * SCALE);
    float e2 = __expf(s2 * SCALE), e3 = __expf(s3 * SCALE);
    sums[p] = e0 + e1 + e2 + e3;
    int slot = head[pbase + p];  // uniform; usually -1
    while (slot >= 0) {          // wave-uniform loop
      *(float4*)(out0 + ((size_t)n * 128 + slot) * (128 * 128) + q0) =
          make_float4(e0, e1, e2, e3);
      slot = nxt[slot];
    }
  }
  __shared__ float part[4][PT];
  const int wave = t >> 6, lane = t & 63;
#pragma unroll
  for (int p = 0; p < PT; ++p) {
    float s = sums[p];
    for (int off = 32; off > 0; off >>= 1) s += __shfl_xor(s, off, 64);
    if (lane == 0) part[wave][p] = s;
  }
  __syncthreads();
  if (t < PT) {
    float tot = part[0][t] + part[1][t] + part[2][t] + part[3][t];
    atomicAdd(l + (size_t)n * HW + pbase + t, tot);
  }
}

// ---------------------------------------------------------------------------
// Kernel D: corr_out[n][c][q] += sum_p otT'[n][p][c] * exp(S'[p][q]).
// Q=4 per thread (float4 fq/acc): halves broadcast-reads-per-FMA vs Q=2;
// per p-iter ~12 LDS issues vs ~360 VALU cyc -> VALU-dominant. LDS-staged
// rows (SCALE folded into f1, rcp(l) into ot), rolled p-loop (keeps VGPR
// sane, r6-proven). Plain launch bounds — r7's forced (256,8) caused the
// VGPR=32 spill catastrophe (1.2 GB FETCH). Grid 4x64x2 = 512 blocks.
#define DPS 64
__global__ __launch_bounds__(256) void k_corrout(
    const float* __restrict__ f1T, const float* __restrict__ f2,
    const float* __restrict__ otT, const float* __restrict__ l,
    float* __restrict__ corr_out) {
  __shared__ float sf1[DPS * PADK];  // 1536 floats
  __shared__ float sot[DPS * PADK];
  const int t = threadIdx.x;
  const int n = blockIdx.z;
  const int q0 = blockIdx.x * 1024 + t * 4;
  const int pbase = blockIdx.y * DPS;
  const float SCALE = 1.0f / sqrtf(21.0f);
  const float4* gf1 = (const float4*)(f1T + ((size_t)n * HW + pbase) * PADK);
  const float4* got = (const float4*)(otT + ((size_t)n * HW + pbase) * PADK);
  const float* lp = l + (size_t)n * HW + pbase;
  for (int o = t; o < 384; o += 256) {
    float4 a = gf1[o];
    a.x *= SCALE; a.y *= SCALE; a.z *= SCALE; a.w *= SCALE;
    ((float4*)sf1)[o] = a;
    float il = fastrcp(lp[o / 6]);  // 6 float4 per PADK row
    float4 v = got[o];
    v.x *= il; v.y *= il; v.z *= il; v.w *= il;
    ((float4*)sot)[o] = v;
  }
  __syncthreads();
  const float* f2n = f2 + (size_t)n * NCL * HW;
  float4 fq[NCL];
#pragma unroll
  for (int k = 0; k < NCL; ++k)
    fq[k] = *(const float4*)(f2n + (size_t)k * HW + q0);
  float4 acc[NCL];
#pragma unroll
  for (int k = 0; k < NCL; ++k) acc[k] = make_float4(0.f, 0.f, 0.f, 0.f);
#pragma unroll 1
  for (int p = 0; p < DPS; ++p) {
    const float* f1p = sf1 + p * PADK;
    const float* otp = sot + p * PADK;
    float s0 = 0.f, s1 = 0.f, s2 = 0.f, s3 = 0.f;
#pragma unroll
    for (int k4 = 0; k4 < 5; ++k4) {
      float4 a = *(const float4*)(f1p + k4 * 4);
#pragma unroll
      for (int j = 0; j < 4; ++j) {
        float aj = (j == 0) ? a.x : (j == 1) ? a.y : (j == 2) ? a.z : a.w;
        const float4 fv = fq[k4 * 4 + j];
        s0 = fmaf(aj, fv.x, s0);
        s1 = fmaf(aj, fv.y, s1);
        s2 = fmaf(aj, fv.z, s2);
        s3 = fmaf(aj, fv.w, s3);
      }
    }
    {
      float a20 = f1p[20];
      const float4 fv = fq[20];
      s0 = fmaf(a20, fv.x, s0);
      s1 = fmaf(a20, fv.y, s1);
      s2 = fmaf(a20, fv.z, s2);
      s3 = fmaf(a20, fv.w, s3);
    }
    float w0 = __expf(s0);
    float w1 = __expf(s1);
    float w2 = __expf(s2);
    float w3 = __expf(s3);
#pragma unroll
    for (int c4 = 0; c4 < 5; ++c4) {
      float4 o = *(const float4*)(otp + c4 * 4);
#pragma unroll
      for (int j = 0; j < 4; ++j) {
        float oj = (j == 0) ? o.x : (j == 1) ? o.y : (j == 2) ? o.z : o.w;
        float4& ac = acc[c4 * 4 + j];
        ac.x = fmaf(oj, w0, ac.x);
        ac.y = fmaf(oj, w1, ac.y);
        ac.z = fmaf(oj, w2, ac.z);
        ac.w = fmaf(oj, w3, ac.w);
      }
    }
    {
      float o20 = otp[20];
      float4& ac = acc[20];
      ac.x = fmaf(o20, w0, ac.x);
      ac.y = fmaf(o20, w1, ac.y);
      ac.z = fmaf(o20, w2, ac.z);
      ac.w = fmaf(o20, w3, ac.w);
    }
  }
  float* co = corr_out + (size_t)n * NCL * HW + q0;
#pragma unroll
  for (int c = 0; c < NCL; ++c) {
    atomicAdd(co + (size_t)c * HW + 0, acc[c].x);
    atomicAdd(co + (size_t)c * HW + 1, acc[c].y);
    atomicAdd(co + (size_t)c * HW + 2, acc[c].z);
    atomicAdd(co + (size_t)c * HW + 3, acc[c].w);
  }
}

// ---------------------------------------------------------------------------
// Kernel E2: parked row -> bilinear 64->128 -> min/max norm -> >0.5 booleans.
__global__ __launch_bounds__(1024) void k_norm(float* __restrict__ out0) {
  __shared__ float row[HW];
  __shared__ float redmn[16], redmx[16];
  __shared__ float wt[128];
  __shared__ int it[128];
  const int t = threadIdx.x;
  const int i = blockIdx.x;
  const int n = blockIdx.y;
  if (t < 128) {
    double s = (double)t * (63.0 / 127.0);
    int i0 = (int)s;
    wt[t] = (float)(s - i0);
    it[t] = i0;
  }
  float* slot = out0 + ((size_t)n * 128 + i) * (128 * 128);
  *(float4*)(row + t * 4) = *(const float4*)(slot + t * 4);
  __syncthreads();
  float vv[16];
  float lmn = 1e30f, lmx = -1e30f;
#pragma unroll
  for (int j = 0; j < 16; ++j) {
    int pix = t + j * 1024;
    int yy = pix >> 7, xx = pix & 127;
    int y0 = it[yy], x0 = it[xx];
    float wy = wt[yy], wx = wt[xx];
    int y1 = min(y0 + 1, 63), x1 = min(x0 + 1, 63);
    float r0 = row[y0 * 64 + x0] * (1.f - wy) + row[y1 * 64 + x0] * wy;
    float r1 = row[y0 * 64 + x1] * (1.f - wy) + row[y1 * 64 + x1] * wy;
    float v = r0 * (1.f - wx) + r1 * wx;
    vv[j] = v;
    lmn = fminf(lmn, v);
    lmx = fmaxf(lmx, v);
  }
  for (int off = 32; off > 0; off >>= 1) {
    lmn = fminf(lmn, __shfl_xor(lmn, off, 64));
    lmx = fmaxf(lmx, __shfl_xor(lmx, off, 64));
  }
  const int wave = t >> 6, lane = t & 63;
  if (lane == 0) { redmn[wave] = lmn; redmx[wave] = lmx; }
  __syncthreads();
  if (t == 0) {
    float mn = redmn[0], mx = redmx[0];
#pragma unroll
    for (int wv = 1; wv < 16; ++wv) {
      mn = fminf(mn, redmn[wv]);
      mx = fmaxf(mx, redmx[wv]);
    }
    redmn[0] = mn;
    redmx[0] = mx;
  }
  __syncthreads();
  const float mn = redmn[0];
  const float rng = redmx[0] - mn;
#pragma unroll
  for (int j = 0; j < 16; ++j) {
    int pix = t + j * 1024;
    float nrm = (vv[j] - mn) / rng;
    slot[pix] = (nrm > 0.5f) ? 1.0f : 0.0f;
  }
}

// ---------------------------------------------------------------------------
extern "C" void kernel_launch(void* const* d_in, const int* in_sizes, int n_in,
                              void* d_out, int out_size, void* d_ws,
                              size_t ws_size, hipStream_t stream) {
  (void)in_sizes; (void)n_in; (void)out_size; (void)ws_size;
  const float* feat = (const float*)d_in[0];
  const float* out  = (const float*)d_in[1];
  const float* w1   = (const float*)d_in[2];
  const float* b1   = (const float*)d_in[3];
  const float* w2   = (const float*)d_in[4];
  const float* b2   = (const float*)d_in[5];
  const int* index  = (const int*)d_in[6];

  float* ws   = (float*)d_ws;
  float* f1T  = ws;                                   // 2*4096*24 = 196608
  float* f2   = ws + 196608;                          // 2*21*4096 = 172032
  float* otT  = ws + 196608 + 172032;                 // 196608
  float* lbuf = ws + 196608 + 172032 + 196608;        // 8192
  int*   head = (int*)(lbuf + 8192);                  // 4096
  int*   nxt  = head + 4096;                          // 128

  float* out0     = (float*)d_out;                    // 2*128*128*128
  float* corr_out = out0 + (size_t)NB * 128 * 128 * 128;  // 2*21*4096

  k_feat<<<dim3(HW / QT, 2), 256, 0, stream>>>(feat, w1, b1, w2, b2, out, f1T,
                                               f2, otT, lbuf, corr_out);
  k_map<<<dim3(1), 1024, 0, stream>>>(index, head, nxt);
  k_stats<<<dim3(HW / PT, 4, 2), 256, 0, stream>>>(f1T, f2, lbuf, head, nxt,
                                                   out0);
  k_corrout<<<dim3(4, HW / DPS, 2), 256, 0, stream>>>(f1T, f2, otT, lbuf,
                                                      corr_out);
  k_norm<<<dim3(128, 2), 1024, 0, stream>>>(out0);
}